// Round 7
// baseline (179.990 us; speedup 1.0000x reference)
//
#include <hip/hip_runtime.h>
#include <math.h>
#include <stdint.h>

#define NUMCH 65
#define THREADS 512
#define WAVES 8
#define NTILE 4
#define CTILE 1024
#define TILE_T (NTILE * CTILE)   // 4096
#define NGRP 16                  // grid 16*8*4 = 512 = exactly 2 blocks/CU (reg-capped 4 waves/SIMD)
#define PLEN 2048
#define MAXP 224

#define XDW 3104                  // packed x-plane dwords (max EN = 16*130+4096+32 = 6208 el / 2)
#define XPHYS 3488                // swizzled plane size: SW(3103)=3487 -> 3488
#define WB_MAX 2128               // 16*130+48
#define BUFDW (2 * XPHYS + WB_MAX) // 9104 dwords per staging buffer
#define SMEM_DW (2 * BUFDW)        // 18208 dwords = 72.8 KiB -> 2 blocks/CU (145.7 <= 160)
#define RSTRIDE 1152               // reduce stride (1024 + swizzle pad); 8*1152=9216 <= SMEM_DW

#define SW(d) ((d) + ((((d) >> 5)) << 2))

struct PTab {
  short c[MAXP], ka[MAXP], len[MAXP], nc[MAXP];
  int start[NGRP + 1];
};

typedef short bf16x8 __attribute__((ext_vector_type(8)));
typedef float f32x16 __attribute__((ext_vector_type(16)));

__global__ void zero_kernel(float* __restrict__ out, int n)
{
  int i = blockIdx.x * blockDim.x + threadIdx.x;
  if (i < n) out[i] = 0.0f;
}

// round-to-nearest-even fp32 -> bf16 bits
__device__ __forceinline__ uint32_t f2bf(float f) {
  uint32_t u = __float_as_uint(f);
  return (u + 0x7FFFu + ((u >> 16) & 1u)) >> 16;
}
// h = bf16(v), l = bf16(v - h)
__device__ __forceinline__ void splithl(float v, uint32_t& h, uint32_t& l) {
  h = f2bf(v);
  l = f2bf(v - __uint_as_float(h << 16));
}
__device__ __forceinline__ uint32_t packhl(float v) {
  uint32_t h, l;
  splithl(v, h, l);
  return h | (l << 16);
}

// Stage one piece's x-window (h/l planes, packed+swizzled) and w-band into a buffer.
// Bounds checks hoisted: d in [dA,dB) has both gi0,gi1 guaranteed in [0,T).
__device__ __forceinline__ void stage_piece(
    uint32_t* __restrict__ xh, uint32_t* __restrict__ xl, uint32_t* __restrict__ wband,
    const float* __restrict__ xc, const float* __restrict__ wc,
    int X0, int T, int XDWn, int WB, int ka, int len, int tid)
{
  int dA = (X0 < 0) ? ((-X0 + 1) >> 1) : 0;
  if (dA > XDWn) dA = XDWn;
  const long hiq = (long)T - 2 - (long)X0;
  int dB = (hiq < 0) ? 0 : (int)(hiq >> 1) + 1;
  if (dB > XDWn) dB = XDWn;
  if (dB < dA) dB = dA;
  for (int d = tid; d < dA; d += THREADS) {           // left edge (checked)
    const int gi0 = X0 + 2 * d, gi1 = gi0 + 1;
    const float v0 = (gi0 >= 0 && gi0 < T) ? xc[gi0] : 0.0f;
    const float v1 = (gi1 >= 0 && gi1 < T) ? xc[gi1] : 0.0f;
    uint32_t h0, l0, h1, l1;
    splithl(v0, h0, l0);
    splithl(v1, h1, l1);
    const int pd = SW(d);
    xh[pd] = h0 | (h1 << 16);
    xl[pd] = l0 | (l1 << 16);
  }
  for (int d = dA + tid; d < dB; d += THREADS) {      // interior (unchecked)
    const float v0 = xc[X0 + 2 * d];
    const float v1 = xc[X0 + 2 * d + 1];
    uint32_t h0, l0, h1, l1;
    splithl(v0, h0, l0);
    splithl(v1, h1, l1);
    const int pd = SW(d);
    xh[pd] = h0 | (h1 << 16);
    xl[pd] = l0 | (l1 << 16);
  }
  for (int d = dB + tid; d < XDWn; d += THREADS) {    // right edge (checked)
    const int gi0 = X0 + 2 * d, gi1 = gi0 + 1;
    const float v0 = (gi0 >= 0 && gi0 < T) ? xc[gi0] : 0.0f;
    const float v1 = (gi1 >= 0 && gi1 < T) ? xc[gi1] : 0.0f;
    uint32_t h0, l0, h1, l1;
    splithl(v0, h0, l0);
    splithl(v1, h1, l1);
    const int pd = SW(d);
    xh[pd] = h0 | (h1 << 16);
    xl[pd] = l0 | (l1 << 16);
  }
  // w band (dword per element, hl-interleaved; zero outside piece)
  for (int d = tid; d < WB; d += THREADS) {
    const int k = ka + d - 32;
    const float v = (d >= 32 && k < ka + len) ? wc[k] : 0.0f;
    wband[d] = packhl(v);
  }
}

// out[b,t] += (1/fs) * sum_c sum_k w[c,k] * x[b,c, t + off_c + k]
// Per chunk ci, tile tau:  C[i][j] += sum_kk A[i][kk]*B[kk][j]
//   A[i][kk] = w[ka+16ci+kk-i] (Toeplitz band), B[kk][j] = x[X0 + 1024*tau + 32j + 16ci + kk]
//   C[i][j] -> out[t0 + 1024*tau + 32j + i]
// Double-buffered pieces: per piece {compute buf[cur]; stage pi+1 -> buf[cur^1];
// ONE barrier}. Staging overlaps other waves' compute tails; barrier count halves.
// At 512 threads the dbuf LDS (72.8 KB) is free: occupancy is reg-capped at
// 4 waves/SIMD (64 acc AGPR + ~60 VGPR = 124/128) -> 2 blocks/CU either way.
// R4 lesson: all inner-loop operand reads stay in LDS.
__global__ __launch_bounds__(THREADS, 4)
void conv_mfma_kernel(const float* __restrict__ inp, const float* __restrict__ w,
                      const int* __restrict__ gidx, const int* __restrict__ fsp,
                      float* __restrict__ out, PTab P, int B, int T, int K)
{
  __shared__ __align__(16) uint32_t smem[SMEM_DW];

  const int g = blockIdx.x, tile4 = blockIdx.y, b = blockIdx.z;
  const int tid = threadIdx.x;
  const int lane = tid & 63;
  const int wv = tid >> 6;
  const int col = lane & 31;
  const int half = lane >> 5;
  const int t0 = tile4 * TILE_T;

  f32x16 acc[NTILE];
  #pragma unroll
  for (int t = 0; t < NTILE; ++t)
    #pragma unroll
    for (int i = 0; i < 16; ++i) acc[t][i] = 0.0f;

  const int s0g = P.start[g], s1g = P.start[g + 1];

  // prologue: stage first piece into buffer 0
  if (s0g < s1g) {
    const int c = P.c[s0g], ka = P.ka[s0g], len = P.len[s0g], nc = P.nc[s0g];
    const int XDWn = (16 * nc + TILE_T + 32 + 1) >> 1;
    const int WB = 16 * nc + 48;
    const int X0 = t0 + gidx[(size_t)c * T] - (K - 1) + ka;
    stage_piece(smem, smem + XPHYS, smem + 2 * XPHYS,
                inp + ((size_t)b * (2 * NUMCH) + c) * T, w + (size_t)c * K,
                X0, T, XDWn, WB, ka, len, tid);
  }
  __syncthreads();

  int cur = 0;
  for (int pi = s0g; pi < s1g; ++pi) {
    const int nc = P.nc[pi];
    const uint32_t* __restrict__ xh = smem + cur * BUFDW;
    const uint32_t* __restrict__ xl = xh + XPHYS;
    const uint32_t* __restrict__ wband = xh + 2 * XPHYS;

    for (int ci = wv; ci < nc; ci += WAVES) {
      // A fragment: 8 hl-dwords, descending addresses -> conflict-free b32 reads
      const int abase = 32 + 16 * ci + 8 * half - col;
      uint32_t ad[8];
      #pragma unroll
      for (int j = 0; j < 8; ++j) ad[j] = wband[abase + j];
      union AU { uint32_t u[4]; bf16x8 v; } Ah, Al;
      #pragma unroll
      for (int j = 0; j < 4; ++j) {
        const uint32_t a0 = ad[2 * j], a1 = ad[2 * j + 1];
        Ah.u[j] = (a0 & 0xFFFFu) | (a1 << 16);
        Al.u[j] = (a0 >> 16) | (a1 & 0xFFFF0000u);
      }
      // B fragments: aligned b128 from packed planes, zero unpack; A shared over 4 tiles
      const int dbase = 16 * col + 4 * half + 8 * ci;
      #pragma unroll
      for (int tau = 0; tau < NTILE; ++tau) {
        const int d = 512 * tau + dbase;
        const int pd = SW(d);
        union BU { uint4 q; bf16x8 v; } Bh, Bl;
        Bh.q = *(const uint4*)&xh[pd];
        Bl.q = *(const uint4*)&xl[pd];
        acc[tau] = __builtin_amdgcn_mfma_f32_32x32x16_bf16(Ah.v, Bh.v, acc[tau], 0, 0, 0);
        acc[tau] = __builtin_amdgcn_mfma_f32_32x32x16_bf16(Ah.v, Bl.v, acc[tau], 0, 0, 0);
        acc[tau] = __builtin_amdgcn_mfma_f32_32x32x16_bf16(Al.v, Bh.v, acc[tau], 0, 0, 0);
      }
    }

    // stage next piece into the other buffer (overlaps other waves' compute tails)
    if (pi + 1 < s1g) {
      const int c2 = P.c[pi + 1], ka2 = P.ka[pi + 1], len2 = P.len[pi + 1], nc2 = P.nc[pi + 1];
      const int XDWn2 = (16 * nc2 + TILE_T + 32 + 1) >> 1;
      const int WB2 = 16 * nc2 + 48;
      const int X02 = t0 + gidx[(size_t)c2 * T] - (K - 1) + ka2;
      uint32_t* yb = smem + (cur ^ 1) * BUFDW;
      stage_piece(yb, yb + XPHYS, yb + 2 * XPHYS,
                  inp + ((size_t)b * (2 * NUMCH) + c2) * T, w + (size_t)c2 * K,
                  X02, T, XDWn2, WB2, ka2, len2, tid);
    }
    __syncthreads();
    cur ^= 1;
  }

  // epilogue: per tile, cross-wave LDS reduce (8 partials) + one atomicAdd per output
  const float inv_fs = 1.0f / (float)fsp[0];
  for (int tau = 0; tau < NTILE; ++tau) {
    #pragma unroll
    for (int r = 0; r < 16; ++r) {
      const int row = (r & 3) + 8 * (r >> 2) + 4 * half;   // verified C/D layout
      const int tl = 32 * col + row;
      smem[wv * RSTRIDE + SW(tl)] = __float_as_uint(acc[tau][r]);
    }
    __syncthreads();
    for (int i = tid; i < CTILE; i += THREADS) {
      const int pidx = SW(i);
      float s = 0.0f;
      #pragma unroll
      for (int r = 0; r < WAVES; ++r)
        s += __uint_as_float(smem[r * RSTRIDE + pidx]);
      atomicAdd(&out[(size_t)b * T + t0 + tau * CTILE + i], s * inv_fs);
    }
    __syncthreads();
  }
}

extern "C" void kernel_launch(void* const* d_in, const int* in_sizes, int n_in,
                              void* d_out, int out_size, void* d_ws, size_t ws_size,
                              hipStream_t stream)
{
  const float* inp = (const float*)d_in[0];
  const float* wgt = (const float*)d_in[1];
  const int* gidx  = (const int*)d_in[2];
  const int* fsp   = (const int*)d_in[3];
  float* out = (float*)d_out;

  const int K = in_sizes[1] / NUMCH;
  const int T = in_sizes[2] / NUMCH;
  const int B = in_sizes[0] / (2 * NUMCH * T);

  // ---- host-side piece construction (analytic gammatone lengths, 48-tap margin) ----
  const double a = pow(10.0, 1.0 / 32.0);
  int pC[MAXP], pKa[MAXP], pLen[MAXP], pNc[MAXP];
  double pW[MAXP];
  int np_ = 0;
  for (int c = 0; c < NUMCH; ++c) {
    int gl = (int)ceil((K / 10.0) * pow(a, 32.0 - c) - 1e-9);
    if (gl > K) gl = K;
    int k0 = K - gl - 48; if (k0 < 0) k0 = 0;
    const int len = K - k0;
    const int npc = (len + PLEN - 1) / PLEN;
    int plen = (len + npc - 1) / npc;
    plen = (plen + 15) & ~15;
    for (int i = 0; i < npc && np_ < MAXP; ++i) {
      const int kai = k0 + i * plen;
      if (kai >= K) break;
      const int li = (K - kai < plen) ? (K - kai) : plen;
      pC[np_] = c; pKa[np_] = kai; pLen[np_] = li;
      pNc[np_] = (li + 15) / 16 + 2;
      // weight = chunk work + staging overhead (overlapped now, but keeps balance sane)
      pW[np_] = (double)pNc[np_] + 20.0;
      ++np_;
    }
  }
  // sort pieces by descending work
  for (int i = 1; i < np_; ++i) {
    int c = pC[i], ka = pKa[i], ln = pLen[i], nc = pNc[i];
    double wv = pW[i];
    int j = i - 1;
    while (j >= 0 && pW[j] < wv) {
      pC[j+1]=pC[j]; pKa[j+1]=pKa[j]; pLen[j+1]=pLen[j]; pNc[j+1]=pNc[j]; pW[j+1]=pW[j]; --j;
    }
    pC[j+1]=c; pKa[j+1]=ka; pLen[j+1]=ln; pNc[j+1]=nc; pW[j+1]=wv;
  }
  // greedy LPT into NGRP groups
  double gsum[NGRP]; int gcnt[NGRP];
  static int glist[NGRP][MAXP];
  for (int g = 0; g < NGRP; ++g) { gsum[g] = 0.0; gcnt[g] = 0; }
  for (int i = 0; i < np_; ++i) {
    int best = 0;
    for (int g = 1; g < NGRP; ++g) if (gsum[g] < gsum[best]) best = g;
    glist[best][gcnt[best]++] = i;
    gsum[best] += pW[i];
  }
  PTab P;
  int p = 0;
  P.start[0] = 0;
  for (int g = 0; g < NGRP; ++g) {
    for (int i = 0; i < gcnt[g]; ++i) {
      const int id = glist[g][i];
      P.c[p] = (short)pC[id]; P.ka[p] = (short)pKa[id];
      P.len[p] = (short)pLen[id]; P.nc[p] = (short)pNc[id];
      ++p;
    }
    P.start[g + 1] = p;
  }
  for (int i = p; i < MAXP; ++i) { P.c[i] = 0; P.ka[i] = 0; P.len[i] = 0; P.nc[i] = 0; }

  zero_kernel<<<(out_size + 255) / 256, 256, 0, stream>>>(out, out_size);
  dim3 grid(NGRP, T / TILE_T, B);
  conv_mfma_kernel<<<grid, THREADS, 0, stream>>>(inp, wgt, gidx, fsp, out, P, B, T, K);
}

// Round 9
// 179.265 us; speedup vs baseline: 1.0040x; 1.0040x over previous
//
#include <hip/hip_runtime.h>
#include <math.h>
#include <stdint.h>

#define NUMCH 65
#define THREADS 512
#define WAVES 8
#define NTILE 4
#define CTILE 1024
#define TILE_T (NTILE * CTILE)   // 4096
#define NGRP 16                  // grid 16*8*4 = 512 = exactly 2 blocks/CU (reg-capped 4 waves/SIMD)
#define PLEN 2048
#define MAXP 224

#define XDW 3104                  // packed x-plane dwords (max EN = 16*130+4096+32 = 6208 el / 2)
#define XPHYS 3488                // swizzled plane size: SW(3103)=3487 -> 3488
#define WB_MAX 2128               // 16*130+48
#define BSTR 1072                 // parity-copy stride (>= WB_MAX/2+1, mult 16)
#define BAND4 (4 * BSTR)          // 4 copies: h-par0, h-par1, l-par0, l-par1
#define RSTRIDE 1152              // reduce stride (1024 + swizzle pad)
#define SMEM_DW (2 * XPHYS + BAND4)  // 11264 dwords = 45.1 KiB; epilogue needs 9216 <= this

#define SW(d) ((d) + ((((d) >> 5)) << 2))

struct PTab {
  short c[MAXP], ka[MAXP], len[MAXP], nc[MAXP];
  int start[NGRP + 1];
};

typedef short bf16x8 __attribute__((ext_vector_type(8)));
typedef float f32x16 __attribute__((ext_vector_type(16)));

__global__ void zero_kernel(float* __restrict__ out, int n)
{
  int i = blockIdx.x * blockDim.x + threadIdx.x;
  if (i < n) out[i] = 0.0f;
}

// round-to-nearest-even fp32 -> bf16 bits
__device__ __forceinline__ uint32_t f2bf(float f) {
  uint32_t u = __float_as_uint(f);
  return (u + 0x7FFFu + ((u >> 16) & 1u)) >> 16;
}
// h = bf16(v), l = bf16(v - h)
__device__ __forceinline__ void splithl(float v, uint32_t& h, uint32_t& l) {
  h = f2bf(v);
  l = f2bf(v - __uint_as_float(h << 16));
}

// Pre-split the w band of each piece into 4 parity copies in global workspace:
//   copy[p][dw] packs band elements (2dw+p, 2dw+p+1); h copies then l copies.
// Band element e in [0, 16nc+48): value = w[ka+e-32] for e in [32, 32+len), else 0.
// A-fragment (8 consecutive elements from abase) then reads as 4 aligned b32 per
// plane from copy (abase&1) with ZERO repack VALU.
__global__ void band_prep(const float* __restrict__ w, uint32_t* __restrict__ bg,
                          PTab P, int K, int np)
{
  const int pi = blockIdx.x;
  if (pi >= np) return;
  const int c = P.c[pi], ka = P.ka[pi], len = P.len[pi];
  const float* __restrict__ wc = w + (size_t)c * K;
  uint32_t* __restrict__ base = bg + (size_t)pi * BAND4;
  for (int i = threadIdx.x; i < 2 * BSTR; i += 256) {
    const int p = i / BSTR, dw = i - p * BSTR;
    const int e0 = 2 * dw + p, e1 = e0 + 1;
    const float v0 = (e0 >= 32 && e0 - 32 < len) ? wc[ka + e0 - 32] : 0.0f;
    const float v1 = (e1 >= 32 && e1 - 32 < len) ? wc[ka + e1 - 32] : 0.0f;
    uint32_t h0, l0, h1, l1;
    splithl(v0, h0, l0);
    splithl(v1, h1, l1);
    base[p * BSTR + dw] = h0 | (h1 << 16);
    base[(2 + p) * BSTR + dw] = l0 | (l1 << 16);
  }
}

// out[b,t] += (1/fs) * sum_c sum_k w[c,k] * x[b,c, t + off_c + k]
// Per chunk ci, tile tau:  C[i][j] += sum_kk A[i][kk]*B[kk][j]
//   A[i][kk] = w[ka+16ci+kk-i] (Toeplitz band), B[kk][j] = x[X0 + 1024*tau + 32j + 16ci + kk]
//   C[i][j] -> out[t0 + 1024*tau + 32j + i]
// Occupancy: acc 64 AGPR + ~56 VGPR -> 4 waves/SIMD hard cap; grid 512 = 2 blocks/CU.
// R4 lesson: all inner-loop operand reads stay in LDS.
// R7 lesson: sync/overlap structure is not the limiter; LDS read pipe is. This
// round halves the A-path cost: parity-copy band (prep kernel) -> 4 aligned b32
// per plane, zero repack VALU, band staged as b128 copies (no packhl).
__global__ __launch_bounds__(THREADS, 4)
void conv_mfma_kernel(const float* __restrict__ inp, const uint32_t* __restrict__ bandg,
                      const int* __restrict__ gidx, const int* __restrict__ fsp,
                      float* __restrict__ out, PTab P, int B, int T, int K)
{
  __shared__ __align__(16) uint32_t smem[SMEM_DW];
  uint32_t* xh = smem;                // packed bf16 h-plane (2 el/dword), swizzled
  uint32_t* xl = smem + XPHYS;        // packed bf16 l-plane
  uint32_t* wband = smem + 2 * XPHYS; // 4 parity copies, BSTR dwords each

  const int g = blockIdx.x, tile4 = blockIdx.y, b = blockIdx.z;
  const int tid = threadIdx.x;
  const int lane = tid & 63;
  const int wv = tid >> 6;
  const int col = lane & 31;
  const int half = lane >> 5;
  const int t0 = tile4 * TILE_T;

  f32x16 acc[NTILE];
  #pragma unroll
  for (int t = 0; t < NTILE; ++t)
    #pragma unroll
    for (int i = 0; i < 16; ++i) acc[t][i] = 0.0f;

  for (int pi = P.start[g]; pi < P.start[g + 1]; ++pi) {
    const int c   = P.c[pi];
    const int ka  = P.ka[pi];
    const int nc  = P.nc[pi];
    const int EN  = 16 * nc + TILE_T + 32;
    const int XDWn = (EN + 1) >> 1;
    const int start_c = gidx[(size_t)c * T];
    const int off = start_c - (K - 1);
    const int X0 = t0 + off + ka;
    const float* __restrict__ xc = inp + ((size_t)b * (2 * NUMCH) + c) * T;
    const uint32_t* __restrict__ bgp = bandg + (size_t)pi * BAND4;

    __syncthreads();
    // stage x: split into h/l planes, 2 elements per dword, swizzled.
    // Bounds checks hoisted: d in [dA,dB) has both gi0,gi1 guaranteed in [0,T).
    int dA = (X0 < 0) ? ((-X0 + 1) >> 1) : 0;
    if (dA > XDWn) dA = XDWn;
    const long hiq = (long)T - 2 - (long)X0;
    int dB = (hiq < 0) ? 0 : (int)(hiq >> 1) + 1;
    if (dB > XDWn) dB = XDWn;
    if (dB < dA) dB = dA;
    for (int d = tid; d < dA; d += THREADS) {           // left edge (checked)
      const int gi0 = X0 + 2 * d, gi1 = gi0 + 1;
      const float v0 = (gi0 >= 0 && gi0 < T) ? xc[gi0] : 0.0f;
      const float v1 = (gi1 >= 0 && gi1 < T) ? xc[gi1] : 0.0f;
      uint32_t h0, l0, h1, l1;
      splithl(v0, h0, l0);
      splithl(v1, h1, l1);
      const int pd = SW(d);
      xh[pd] = h0 | (h1 << 16);
      xl[pd] = l0 | (l1 << 16);
    }
    for (int d = dA + tid; d < dB; d += THREADS) {      // interior (unchecked)
      const float v0 = xc[X0 + 2 * d];
      const float v1 = xc[X0 + 2 * d + 1];
      uint32_t h0, l0, h1, l1;
      splithl(v0, h0, l0);
      splithl(v1, h1, l1);
      const int pd = SW(d);
      xh[pd] = h0 | (h1 << 16);
      xl[pd] = l0 | (l1 << 16);
    }
    for (int d = dB + tid; d < XDWn; d += THREADS) {    // right edge (checked)
      const int gi0 = X0 + 2 * d, gi1 = gi0 + 1;
      const float v0 = (gi0 >= 0 && gi0 < T) ? xc[gi0] : 0.0f;
      const float v1 = (gi1 >= 0 && gi1 < T) ? xc[gi1] : 0.0f;
      uint32_t h0, l0, h1, l1;
      splithl(v0, h0, l0);
      splithl(v1, h1, l1);
      const int pd = SW(d);
      xh[pd] = h0 | (h1 << 16);
      xl[pd] = l0 | (l1 << 16);
    }
    // stage the 4 parity band copies via plain b128 copies (no VALU)
    for (int i = tid; i < (BAND4 >> 2); i += THREADS) {
      *(uint4*)&wband[4 * i] = *(const uint4*)&bgp[4 * i];
    }
    __syncthreads();

    for (int ci = wv; ci < nc; ci += WAVES) {
      // A fragment: 4 aligned b32 per plane from parity copy; zero repack
      const int abase = 32 + 16 * ci + 8 * half - col;
      const int par = abase & 1;
      const int adw = (abase - par) >> 1;
      const uint32_t* __restrict__ hb = wband + par * BSTR;
      const uint32_t* __restrict__ lb = wband + (2 + par) * BSTR;
      union AU { uint32_t u[4]; bf16x8 v; } Ah, Al;
      #pragma unroll
      for (int q = 0; q < 4; ++q) {
        Ah.u[q] = hb[adw + q];
        Al.u[q] = lb[adw + q];
      }
      // B fragments: aligned b128 from packed planes, zero unpack; A shared over 4 tiles
      const int dbase = 16 * col + 4 * half + 8 * ci;
      #pragma unroll
      for (int tau = 0; tau < NTILE; ++tau) {
        const int d = 512 * tau + dbase;
        const int pd = SW(d);
        union BU { uint4 q; bf16x8 v; } Bh, Bl;
        Bh.q = *(const uint4*)&xh[pd];
        Bl.q = *(const uint4*)&xl[pd];
        acc[tau] = __builtin_amdgcn_mfma_f32_32x32x16_bf16(Ah.v, Bh.v, acc[tau], 0, 0, 0);
        acc[tau] = __builtin_amdgcn_mfma_f32_32x32x16_bf16(Ah.v, Bl.v, acc[tau], 0, 0, 0);
        acc[tau] = __builtin_amdgcn_mfma_f32_32x32x16_bf16(Al.v, Bh.v, acc[tau], 0, 0, 0);
      }
    }
  }

  // epilogue: per tile, cross-wave LDS reduce (8 partials) + one atomicAdd per output
  __syncthreads();
  const float inv_fs = 1.0f / (float)fsp[0];
  for (int tau = 0; tau < NTILE; ++tau) {
    #pragma unroll
    for (int r = 0; r < 16; ++r) {
      const int row = (r & 3) + 8 * (r >> 2) + 4 * half;   // verified C/D layout
      const int tl = 32 * col + row;
      smem[wv * RSTRIDE + SW(tl)] = __float_as_uint(acc[tau][r]);
    }
    __syncthreads();
    for (int i = tid; i < CTILE; i += THREADS) {
      const int pidx = SW(i);
      float s = 0.0f;
      #pragma unroll
      for (int r = 0; r < WAVES; ++r)
        s += __uint_as_float(smem[r * RSTRIDE + pidx]);
      atomicAdd(&out[(size_t)b * T + t0 + tau * CTILE + i], s * inv_fs);
    }
    __syncthreads();
  }
}

extern "C" void kernel_launch(void* const* d_in, const int* in_sizes, int n_in,
                              void* d_out, int out_size, void* d_ws, size_t ws_size,
                              hipStream_t stream)
{
  const float* inp = (const float*)d_in[0];
  const float* wgt = (const float*)d_in[1];
  const int* gidx  = (const int*)d_in[2];
  const int* fsp   = (const int*)d_in[3];
  float* out = (float*)d_out;

  const int K = in_sizes[1] / NUMCH;
  const int T = in_sizes[2] / NUMCH;
  const int B = in_sizes[0] / (2 * NUMCH * T);

  // ---- host-side piece construction (analytic gammatone lengths, 48-tap margin) ----
  const double a = pow(10.0, 1.0 / 32.0);
  int pC[MAXP], pKa[MAXP], pLen[MAXP], pNc[MAXP];
  double pW[MAXP];
  int np_ = 0;
  for (int c = 0; c < NUMCH; ++c) {
    int gl = (int)ceil((K / 10.0) * pow(a, 32.0 - c) - 1e-9);
    if (gl > K) gl = K;
    int k0 = K - gl - 48; if (k0 < 0) k0 = 0;
    const int len = K - k0;
    const int npc = (len + PLEN - 1) / PLEN;
    int plen = (len + npc - 1) / npc;
    plen = (plen + 15) & ~15;
    for (int i = 0; i < npc && np_ < MAXP; ++i) {
      const int kai = k0 + i * plen;
      if (kai >= K) break;
      const int li = (K - kai < plen) ? (K - kai) : plen;
      pC[np_] = c; pKa[np_] = kai; pLen[np_] = li;
      pNc[np_] = (li + 15) / 16 + 2;
      // weight = chunk work + fixed staging overhead (~4128-el window)
      pW[np_] = (double)pNc[np_] + 20.0;
      ++np_;
    }
  }
  // sort pieces by descending work
  for (int i = 1; i < np_; ++i) {
    int c = pC[i], ka = pKa[i], ln = pLen[i], nc = pNc[i];
    double wv = pW[i];
    int j = i - 1;
    while (j >= 0 && pW[j] < wv) {
      pC[j+1]=pC[j]; pKa[j+1]=pKa[j]; pLen[j+1]=pLen[j]; pNc[j+1]=pNc[j]; pW[j+1]=pW[j]; --j;
    }
    pC[j+1]=c; pKa[j+1]=ka; pLen[j+1]=ln; pNc[j+1]=nc; pW[j+1]=wv;
  }
  // greedy LPT into NGRP groups
  double gsum[NGRP]; int gcnt[NGRP];
  static int glist[NGRP][MAXP];
  for (int g = 0; g < NGRP; ++g) { gsum[g] = 0.0; gcnt[g] = 0; }
  for (int i = 0; i < np_; ++i) {
    int best = 0;
    for (int g = 1; g < NGRP; ++g) if (gsum[g] < gsum[best]) best = g;
    glist[best][gcnt[best]++] = i;
    gsum[best] += pW[i];
  }
  PTab P;
  int p = 0;
  P.start[0] = 0;
  for (int g = 0; g < NGRP; ++g) {
    for (int i = 0; i < gcnt[g]; ++i) {
      const int id = glist[g][i];
      P.c[p] = (short)pC[id]; P.ka[p] = (short)pKa[id];
      P.len[p] = (short)pLen[id]; P.nc[p] = (short)pNc[id];
      ++p;
    }
    P.start[g + 1] = p;
  }
  for (int i = p; i < MAXP; ++i) { P.c[i] = 0; P.ka[i] = 0; P.len[i] = 0; P.nc[i] = 0; }

  // workspace: parity band copies, MAXP * BAND4 dwords (~3.9 MB)
  zero_kernel<<<(out_size + 255) / 256, 256, 0, stream>>>(out, out_size);
  band_prep<<<np_, 256, 0, stream>>>(wgt, (uint32_t*)d_ws, P, K, np_);
  dim3 grid(NGRP, T / TILE_T, B);
  conv_mfma_kernel<<<grid, THREADS, 0, stream>>>(inp, (const uint32_t*)d_ws, gidx, fsp, out, P, B, T, K);
}

// Round 10
// 179.009 us; speedup vs baseline: 1.0055x; 1.0014x over previous
//
#include <hip/hip_runtime.h>
#include <math.h>
#include <stdint.h>

#define NUMCH 65
#define THREADS 512
#define WAVES 8
#define NTILE 4
#define CTILE 1024
#define TILE_T (NTILE * CTILE)   // 4096
#define NGRP 16                  // grid 16*8*4 = 512 = exactly 2 blocks/CU (reg-capped 4 waves/SIMD)
#define PLEN 2048
#define MAXP 224

#define XDW 3104                  // packed x-plane dwords (max EN = 16*130+4096+32 = 6208 el / 2)
#define XPHYS 3488                // swizzled plane size: SW(3103)=3487 -> 3488
#define WB_MAX 2128               // 16*130+48
#define BSTR 1072                 // parity-copy stride (>= WB_MAX/2+1, mult 16)
#define BAND4 (4 * BSTR)          // 4 copies: h-par0, h-par1, l-par0, l-par1
#define RSTRIDE 1152              // reduce stride (1024 + swizzle pad)
#define SMEM_DW (2 * XPHYS + BAND4)  // 11264 dwords = 45.1 KiB; epilogue needs 9216 <= this

#define SW(d) ((d) + ((((d) >> 5)) << 2))

struct PTab {
  short c[MAXP], ka[MAXP], len[MAXP], nc[MAXP];
  int start[NGRP + 1];
};

typedef short bf16x8 __attribute__((ext_vector_type(8)));
typedef float f32x16 __attribute__((ext_vector_type(16)));

__global__ void zero_kernel(float* __restrict__ out, int n)
{
  int i = blockIdx.x * blockDim.x + threadIdx.x;
  if (i < n) out[i] = 0.0f;
}

// round-to-nearest-even fp32 -> bf16 bits (host-prep path)
__device__ __forceinline__ uint32_t f2bf(float f) {
  uint32_t u = __float_as_uint(f);
  return (u + 0x7FFFu + ((u >> 16) & 1u)) >> 16;
}
// h = bf16(v), l = bf16(v - h)
__device__ __forceinline__ void splithl(float v, uint32_t& h, uint32_t& l) {
  h = f2bf(v);
  l = f2bf(v - __uint_as_float(h << 16));
}

// Hot-path hl-split of a float pair via v_cvt_pk_bf16_f32 (1 instr replaces ~10
// bit-ops per element; RNE rounding identical to f2bf). hp = bf16(v0)|bf16(v1)<<16,
// lp = packed bf16 of the residuals.
__device__ __forceinline__ void packpair(float v0, float v1, uint32_t& hp, uint32_t& lp) {
  uint32_t h;
  asm("v_cvt_pk_bf16_f32 %0, %1, %2" : "=v"(h) : "v"(v0), "v"(v1));
  const float h0 = __uint_as_float(h << 16);
  const float h1 = __uint_as_float(h & 0xFFFF0000u);
  uint32_t l;
  asm("v_cvt_pk_bf16_f32 %0, %1, %2" : "=v"(l) : "v"(v0 - h0), "v"(v1 - h1));
  hp = h; lp = l;
}

// Pre-split the w band of each piece into 4 parity copies in global workspace:
//   copy[p][dw] packs band elements (2dw+p, 2dw+p+1); h copies then l copies.
// Band element e in [0, 16nc+48): value = w[ka+e-32] for e in [32, 32+len), else 0.
// A-fragment (8 consecutive elements from abase) then reads as 4 aligned b32 per
// plane from copy (abase&1) with ZERO repack VALU.
__global__ void band_prep(const float* __restrict__ w, uint32_t* __restrict__ bg,
                          PTab P, int K, int np)
{
  const int pi = blockIdx.x;
  if (pi >= np) return;
  const int c = P.c[pi], ka = P.ka[pi], len = P.len[pi];
  const float* __restrict__ wc = w + (size_t)c * K;
  uint32_t* __restrict__ base = bg + (size_t)pi * BAND4;
  for (int i = threadIdx.x; i < 2 * BSTR; i += 256) {
    const int p = i / BSTR, dw = i - p * BSTR;
    const int e0 = 2 * dw + p, e1 = e0 + 1;
    const float v0 = (e0 >= 32 && e0 - 32 < len) ? wc[ka + e0 - 32] : 0.0f;
    const float v1 = (e1 >= 32 && e1 - 32 < len) ? wc[ka + e1 - 32] : 0.0f;
    uint32_t h0, l0, h1, l1;
    splithl(v0, h0, l0);
    splithl(v1, h1, l1);
    base[p * BSTR + dw] = h0 | (h1 << 16);
    base[(2 + p) * BSTR + dw] = l0 | (l1 << 16);
  }
}

// out[b,t] += (1/fs) * sum_c sum_k w[c,k] * x[b,c, t + off_c + k]
// Per chunk ci, tile tau:  C[i][j] += sum_kk A[i][kk]*B[kk][j]
//   A[i][kk] = w[ka+16ci+kk-i] (Toeplitz band), B[kk][j] = x[X0 + 1024*tau + 32j + 16ci + kk]
//   C[i][j] -> out[t0 + 1024*tau + 32j + i]
// Occupancy: acc 64 AGPR + 64 VGPR = 128 unified -> exactly 4 waves/SIMD (bounds-capped).
// R4 lesson: all inner-loop operand reads stay in LDS.
// R6/R7 lesson: staging phases are ISSUE-bound (VALU), not latency/barrier-bound.
// R10: staging hl-split via v_cvt_pk_bf16_f32 (6 VALU per dword-pair vs ~24).
__global__ __launch_bounds__(THREADS, 4)
void conv_mfma_kernel(const float* __restrict__ inp, const uint32_t* __restrict__ bandg,
                      const int* __restrict__ gidx, const int* __restrict__ fsp,
                      float* __restrict__ out, PTab P, int B, int T, int K)
{
  __shared__ __align__(16) uint32_t smem[SMEM_DW];
  uint32_t* xh = smem;                // packed bf16 h-plane (2 el/dword), swizzled
  uint32_t* xl = smem + XPHYS;        // packed bf16 l-plane
  uint32_t* wband = smem + 2 * XPHYS; // 4 parity copies, BSTR dwords each

  const int g = blockIdx.x, tile4 = blockIdx.y, b = blockIdx.z;
  const int tid = threadIdx.x;
  const int lane = tid & 63;
  const int wv = tid >> 6;
  const int col = lane & 31;
  const int half = lane >> 5;
  const int t0 = tile4 * TILE_T;

  f32x16 acc[NTILE];
  #pragma unroll
  for (int t = 0; t < NTILE; ++t)
    #pragma unroll
    for (int i = 0; i < 16; ++i) acc[t][i] = 0.0f;

  for (int pi = P.start[g]; pi < P.start[g + 1]; ++pi) {
    const int c   = P.c[pi];
    const int ka  = P.ka[pi];
    const int nc  = P.nc[pi];
    const int EN  = 16 * nc + TILE_T + 32;
    const int XDWn = (EN + 1) >> 1;
    const int start_c = gidx[(size_t)c * T];
    const int off = start_c - (K - 1);
    const int X0 = t0 + off + ka;
    const float* __restrict__ xc = inp + ((size_t)b * (2 * NUMCH) + c) * T;
    const uint32_t* __restrict__ bgp = bandg + (size_t)pi * BAND4;

    __syncthreads();
    // stage x: split into h/l planes, 2 elements per dword, swizzled.
    // Bounds checks hoisted: d in [dA,dB) has both gi0,gi1 guaranteed in [0,T).
    int dA = (X0 < 0) ? ((-X0 + 1) >> 1) : 0;
    if (dA > XDWn) dA = XDWn;
    const long hiq = (long)T - 2 - (long)X0;
    int dB = (hiq < 0) ? 0 : (int)(hiq >> 1) + 1;
    if (dB > XDWn) dB = XDWn;
    if (dB < dA) dB = dA;
    for (int d = tid; d < dA; d += THREADS) {           // left edge (checked)
      const int gi0 = X0 + 2 * d, gi1 = gi0 + 1;
      const float v0 = (gi0 >= 0 && gi0 < T) ? xc[gi0] : 0.0f;
      const float v1 = (gi1 >= 0 && gi1 < T) ? xc[gi1] : 0.0f;
      uint32_t hp, lp;
      packpair(v0, v1, hp, lp);
      const int pd = SW(d);
      xh[pd] = hp;
      xl[pd] = lp;
    }
    for (int d = dA + tid; d < dB; d += THREADS) {      // interior (unchecked)
      const float v0 = xc[X0 + 2 * d];
      const float v1 = xc[X0 + 2 * d + 1];
      uint32_t hp, lp;
      packpair(v0, v1, hp, lp);
      const int pd = SW(d);
      xh[pd] = hp;
      xl[pd] = lp;
    }
    for (int d = dB + tid; d < XDWn; d += THREADS) {    // right edge (checked)
      const int gi0 = X0 + 2 * d, gi1 = gi0 + 1;
      const float v0 = (gi0 >= 0 && gi0 < T) ? xc[gi0] : 0.0f;
      const float v1 = (gi1 >= 0 && gi1 < T) ? xc[gi1] : 0.0f;
      uint32_t hp, lp;
      packpair(v0, v1, hp, lp);
      const int pd = SW(d);
      xh[pd] = hp;
      xl[pd] = lp;
    }
    // stage the 4 parity band copies via plain b128 copies (no VALU)
    for (int i = tid; i < (BAND4 >> 2); i += THREADS) {
      *(uint4*)&wband[4 * i] = *(const uint4*)&bgp[4 * i];
    }
    __syncthreads();

    for (int ci = wv; ci < nc; ci += WAVES) {
      // A fragment: 4 aligned b32 per plane from parity copy; zero repack
      const int abase = 32 + 16 * ci + 8 * half - col;
      const int par = abase & 1;
      const int adw = (abase - par) >> 1;
      const uint32_t* __restrict__ hb = wband + par * BSTR;
      const uint32_t* __restrict__ lb = wband + (2 + par) * BSTR;
      union AU { uint32_t u[4]; bf16x8 v; } Ah, Al;
      #pragma unroll
      for (int q = 0; q < 4; ++q) {
        Ah.u[q] = hb[adw + q];
        Al.u[q] = lb[adw + q];
      }
      // B fragments: aligned b128 from packed planes, zero unpack; A shared over 4 tiles
      const int dbase = 16 * col + 4 * half + 8 * ci;
      #pragma unroll
      for (int tau = 0; tau < NTILE; ++tau) {
        const int d = 512 * tau + dbase;
        const int pd = SW(d);
        union BU { uint4 q; bf16x8 v; } Bh, Bl;
        Bh.q = *(const uint4*)&xh[pd];
        Bl.q = *(const uint4*)&xl[pd];
        acc[tau] = __builtin_amdgcn_mfma_f32_32x32x16_bf16(Ah.v, Bh.v, acc[tau], 0, 0, 0);
        acc[tau] = __builtin_amdgcn_mfma_f32_32x32x16_bf16(Ah.v, Bl.v, acc[tau], 0, 0, 0);
        acc[tau] = __builtin_amdgcn_mfma_f32_32x32x16_bf16(Al.v, Bh.v, acc[tau], 0, 0, 0);
      }
    }
  }

  // epilogue: per tile, cross-wave LDS reduce (8 partials) + one atomicAdd per output
  __syncthreads();
  const float inv_fs = 1.0f / (float)fsp[0];
  for (int tau = 0; tau < NTILE; ++tau) {
    #pragma unroll
    for (int r = 0; r < 16; ++r) {
      const int row = (r & 3) + 8 * (r >> 2) + 4 * half;   // verified C/D layout
      const int tl = 32 * col + row;
      smem[wv * RSTRIDE + SW(tl)] = __float_as_uint(acc[tau][r]);
    }
    __syncthreads();
    for (int i = tid; i < CTILE; i += THREADS) {
      const int pidx = SW(i);
      float s = 0.0f;
      #pragma unroll
      for (int r = 0; r < WAVES; ++r)
        s += __uint_as_float(smem[r * RSTRIDE + pidx]);
      atomicAdd(&out[(size_t)b * T + t0 + tau * CTILE + i], s * inv_fs);
    }
    __syncthreads();
  }
}

extern "C" void kernel_launch(void* const* d_in, const int* in_sizes, int n_in,
                              void* d_out, int out_size, void* d_ws, size_t ws_size,
                              hipStream_t stream)
{
  const float* inp = (const float*)d_in[0];
  const float* wgt = (const float*)d_in[1];
  const int* gidx  = (const int*)d_in[2];
  const int* fsp   = (const int*)d_in[3];
  float* out = (float*)d_out;

  const int K = in_sizes[1] / NUMCH;
  const int T = in_sizes[2] / NUMCH;
  const int B = in_sizes[0] / (2 * NUMCH * T);

  // ---- host-side piece construction (analytic gammatone lengths, 48-tap margin) ----
  const double a = pow(10.0, 1.0 / 32.0);
  int pC[MAXP], pKa[MAXP], pLen[MAXP], pNc[MAXP];
  double pW[MAXP];
  int np_ = 0;
  for (int c = 0; c < NUMCH; ++c) {
    int gl = (int)ceil((K / 10.0) * pow(a, 32.0 - c) - 1e-9);
    if (gl > K) gl = K;
    int k0 = K - gl - 48; if (k0 < 0) k0 = 0;
    const int len = K - k0;
    const int npc = (len + PLEN - 1) / PLEN;
    int plen = (len + npc - 1) / npc;
    plen = (plen + 15) & ~15;
    for (int i = 0; i < npc && np_ < MAXP; ++i) {
      const int kai = k0 + i * plen;
      if (kai >= K) break;
      const int li = (K - kai < plen) ? (K - kai) : plen;
      pC[np_] = c; pKa[np_] = kai; pLen[np_] = li;
      pNc[np_] = (li + 15) / 16 + 2;
      // weight = chunk work + fixed staging overhead (~4128-el window)
      pW[np_] = (double)pNc[np_] + 20.0;
      ++np_;
    }
  }
  // sort pieces by descending work
  for (int i = 1; i < np_; ++i) {
    int c = pC[i], ka = pKa[i], ln = pLen[i], nc = pNc[i];
    double wv = pW[i];
    int j = i - 1;
    while (j >= 0 && pW[j] < wv) {
      pC[j+1]=pC[j]; pKa[j+1]=pKa[j]; pLen[j+1]=pLen[j]; pNc[j+1]=pNc[j]; pW[j+1]=pW[j]; --j;
    }
    pC[j+1]=c; pKa[j+1]=ka; pLen[j+1]=ln; pNc[j+1]=nc; pW[j+1]=wv;
  }
  // greedy LPT into NGRP groups
  double gsum[NGRP]; int gcnt[NGRP];
  static int glist[NGRP][MAXP];
  for (int g = 0; g < NGRP; ++g) { gsum[g] = 0.0; gcnt[g] = 0; }
  for (int i = 0; i < np_; ++i) {
    int best = 0;
    for (int g = 1; g < NGRP; ++g) if (gsum[g] < gsum[best]) best = g;
    glist[best][gcnt[best]++] = i;
    gsum[best] += pW[i];
  }
  PTab P;
  int p = 0;
  P.start[0] = 0;
  for (int g = 0; g < NGRP; ++g) {
    for (int i = 0; i < gcnt[g]; ++i) {
      const int id = glist[g][i];
      P.c[p] = (short)pC[id]; P.ka[p] = (short)pKa[id];
      P.len[p] = (short)pLen[id]; P.nc[p] = (short)pNc[id];
      ++p;
    }
    P.start[g + 1] = p;
  }
  for (int i = p; i < MAXP; ++i) { P.c[i] = 0; P.ka[i] = 0; P.len[i] = 0; P.nc[i] = 0; }

  // workspace: parity band copies, MAXP * BAND4 dwords (~3.9 MB)
  zero_kernel<<<(out_size + 255) / 256, 256, 0, stream>>>(out, out_size);
  band_prep<<<np_, 256, 0, stream>>>(wgt, (uint32_t*)d_ws, P, K, np_);
  dim3 grid(NGRP, T / TILE_T, B);
  conv_mfma_kernel<<<grid, THREADS, 0, stream>>>(inp, (const uint32_t*)d_ws, gidx, fsp, out, P, B, T, K);
}